// Round 6
// baseline (551.751 us; speedup 1.0000x reference)
//
#include <hip/hip_runtime.h>
#include <hip/hip_bf16.h>

#define BB 4      // batch
#define SS 1023   // source length = 2T-1
#define TT 512    // window length
#define CC 1024   // embed dim
#define DD 64     // head size
#define NROW (BB*SS)    // 4092
#define PR 8            // proj rows per block
#define PBLOCKS ((NROW + PR - 1) / PR)   // 512
#define WT 4            // attn windows per block

typedef float f4 __attribute__((ext_vector_type(4)));

// ---------------------------------------------------------------------------
// Kernel 1: projections k|v|q = x @ [Wk|Wv|Wq].
// 512 blocks x 512 threads (8 waves). Block owns PR=8 x-rows staged once in
// 32 KB LDS. Wave wv covers K-slice [128wv, 128wv+128); lane = output d.
// W loads are software-pipelined through two register banks (A/B), manual
// unroll x2, so ~24 L2 loads stay in flight under the FMA blocks.
// k stored transposed kT[d][row] for coalesced attn phase-1.
// ---------------------------------------------------------------------------
__global__ __launch_bounds__(512, 4) void proj_kernel(
    const float* __restrict__ x,
    const float* __restrict__ Wk,
    const float* __restrict__ Wv,
    const float* __restrict__ Wq,
    float* __restrict__ kT,     // [DD][NROW]
    float* __restrict__ vbuf,   // [NROW][DD]
    float* __restrict__ qbuf)   // [BB*TT][DD]
{
    __shared__ __align__(16) float smem[PR * CC];   // 32 KB; later red[4][1536]

    const int tid  = threadIdx.x;
    const int lane = tid & 63;
    const int wv   = tid >> 6;              // 0..7
    const int bs0  = blockIdx.x * PR;
    const int nr   = (NROW - bs0 < PR) ? (NROW - bs0) : PR;
    const int s0   = bs0 % SS;
    const bool needq = (s0 + PR - 1) >= (TT - 1);

    // ---- stage x panel: 8 rows x 1024 floats, coalesced f4 ----
    {
        const f4* xg = (const f4*)x;
        f4* xs4 = (f4*)smem;
#pragma unroll
        for (int j = 0; j < 4; ++j) {
            const int idx = tid + j * 512;         // 0..2047
            const int r = idx >> 8, c4 = idx & 255;
            int g = bs0 + r; if (g > NROW - 1) g = NROW - 1;
            xs4[idx] = xg[(size_t)g * (CC / 4) + c4];
        }
    }
    __syncthreads();

    float accK[PR], accV[PR], accQ[PR];
#pragma unroll
    for (int r = 0; r < PR; ++r) { accK[r] = 0.f; accV[r] = 0.f; accQ[r] = 0.f; }

    const int c0 = wv * 128;
    const float* wkp = Wk + (size_t)c0 * DD + lane;
    const float* wvp = Wv + (size_t)c0 * DD + lane;
    const float* wqp = Wq + (size_t)c0 * DD + lane;

    auto loadW = [&](float wk[4], float wl[4], float wq[4], int c4) {
#pragma unroll
        for (int kk = 0; kk < 4; ++kk) {
            const int cl = c4 * 4 + kk;
            wk[kk] = wkp[cl * DD];
            wl[kk] = wvp[cl * DD];
            if (needq) wq[kk] = wqp[cl * DD];
        }
    };
    auto fmaStep = [&](const float wk[4], const float wl[4], const float wq[4],
                       int c4) {
        f4 xv[PR];
#pragma unroll
        for (int r = 0; r < PR; ++r)
            xv[r] = *(const f4*)&smem[r * CC + c0 + c4 * 4];
#pragma unroll
        for (int kk = 0; kk < 4; ++kk) {
#pragma unroll
            for (int r = 0; r < PR; ++r) {
                accK[r] = fmaf(xv[r][kk], wk[kk], accK[r]);
                accV[r] = fmaf(xv[r][kk], wl[kk], accV[r]);
            }
        }
        if (needq) {
#pragma unroll
            for (int kk = 0; kk < 4; ++kk)
#pragma unroll
                for (int r = 0; r < PR; ++r)
                    accQ[r] = fmaf(xv[r][kk], wq[kk], accQ[r]);
        }
    };

    float wkA[4], wlA[4], wqA[4], wkB[4], wlB[4], wqB[4];
    loadW(wkA, wlA, wqA, 0);
    for (int c4 = 0; c4 < 32; c4 += 2) {
        loadW(wkB, wlB, wqB, c4 + 1);
        fmaStep(wkA, wlA, wqA, c4);
        loadW(wkA, wlA, wqA, (c4 + 2 < 32) ? (c4 + 2) : 0);  // tail: harmless
        fmaStep(wkB, wlB, wqB, c4 + 1);
    }
    __syncthreads();            // x panel no longer needed -> reuse as red

    // ---- cross-wave reduction: red[4][1536], waves 4-7 add onto 0-3 ----
    float* red = smem;
    const int base = (wv & 3) * 1536;
    if (wv < 4) {
#pragma unroll
        for (int r = 0; r < PR; ++r) {
            red[base + lane * PR + r]        = accK[r];   // k: [d][r]
            red[base + 512 + r * DD + lane]  = accV[r];   // v: [r][d]
        }
        if (needq)
#pragma unroll
            for (int r = 0; r < PR; ++r)
                red[base + 1024 + r * DD + lane] = accQ[r];
    }
    __syncthreads();
    if (wv >= 4) {
#pragma unroll
        for (int r = 0; r < PR; ++r) {
            red[base + lane * PR + r]       += accK[r];
            red[base + 512 + r * DD + lane] += accV[r];
        }
        if (needq)
#pragma unroll
            for (int r = 0; r < PR; ++r)
                red[base + 1024 + r * DD + lane] += accQ[r];
    }
    __syncthreads();

    // ---- final 4-way sum + stores ----
    const int nslots = needq ? 1536 : 1024;
    for (int slot = tid; slot < nslots; slot += 512) {
        const float s = red[slot] + red[slot + 1536] +
                        red[slot + 3072] + red[slot + 4608];
        if (slot < 512) {
            const int dd = slot >> 3, r = slot & 7;
            if (r < nr) kT[(size_t)dd * NROW + bs0 + r] = s;
        } else if (slot < 1024) {
            const int i = slot - 512, r = i >> 6, dd = i & 63;
            if (r < nr) vbuf[(size_t)(bs0 + r) * DD + dd] = s;
        } else {
            const int i = slot - 1024, r = i >> 6, dd = i & 63;
            if (r < nr) {
                const int bs = bs0 + r;
                const int b = bs / SS, ss = bs - b * SS;
                if (ss >= TT - 1)
                    qbuf[((size_t)b * TT + (ss - (TT - 1))) * DD + dd] = s;
            }
        }
    }
}

// ---------------------------------------------------------------------------
// Kernel 2: attention, WT=4 windows per block, 512 blocks x 512 threads.
// Phase 1: thread owns t = tid; 4 overlapping k loads (L1-hit) serve the 4
//          windows; bias folded into the FMA (1 load, shared across m).
// Softmax: wave m (<4) reduces row m.
// Phase 2: wave wv covers t-slice [64wv, 64wv+64); sliding v regs serve 4 m.
// ---------------------------------------------------------------------------
__global__ __launch_bounds__(512) void attn_kernel(
    const float* __restrict__ kT,     // [DD][NROW]
    const float* __restrict__ vbuf,   // [NROW][DD]
    const float* __restrict__ qbuf,   // [BB*TT][DD]
    const float* __restrict__ bias,   // [DD][TT]
    float* __restrict__ out)          // [BB*TT][DD]
{
    __shared__ __align__(16) float qsT[DD][WT];       // 1 KB  [d][m]
    __shared__ float logit[WT][TT];                   // 8 KB
    __shared__ __align__(16) float weiT[TT][WT];      // 8 KB  [t][m]
    __shared__ float invs[WT];
    __shared__ float partial[8][WT][DD];              // 8 KB

    const int tid  = threadIdx.x;
    const int lane = tid & 63;
    const int wv   = tid >> 6;          // 0..7
    const int blk  = blockIdx.x;
    const int b    = blk >> 7;          // 128 blocks per batch
    const int w0   = (blk & 127) * WT;

    if (tid < WT * DD) {
        const int m = tid >> 6, dd = tid & 63;
        qsT[dd][m] = qbuf[((size_t)b * TT + w0 + m) * DD + dd];
    }
    __syncthreads();

    // ---- phase 1: logits, t = tid ----
    {
        const int t = tid;
        const float* kcol = kT + (size_t)b * SS + w0 + t;
        const float* bp   = bias + t;
        float acc0 = 0.f, acc1 = 0.f, acc2 = 0.f, acc3 = 0.f;
#pragma unroll 4
        for (int dd = 0; dd < DD; ++dd) {
            const float b0 = bp[dd * TT];
            const f4 qv = *(const f4*)&qsT[dd][0];
            const float* kr = kcol + (size_t)dd * NROW;
            const float k0 = kr[0], k1 = kr[1], k2 = kr[2], k3 = kr[3];
            acc0 = fmaf(qv[0], k0 + b0, acc0);
            acc1 = fmaf(qv[1], k1 + b0, acc1);
            acc2 = fmaf(qv[2], k2 + b0, acc2);
            acc3 = fmaf(qv[3], k3 + b0, acc3);
        }
        logit[0][t] = acc0; logit[1][t] = acc1;
        logit[2][t] = acc2; logit[3][t] = acc3;
    }
    __syncthreads();

    // ---- softmax: wave wv (<4) owns row wv ----
    if (wv < WT) {
        const float* row = logit[wv];
        float r[8];
        float mx = -1e30f;
#pragma unroll
        for (int j = 0; j < 8; ++j) {
            r[j] = row[lane + 64 * j];
            mx = fmaxf(mx, r[j]);
        }
#pragma unroll
        for (int off = 1; off < 64; off <<= 1)
            mx = fmaxf(mx, __shfl_xor(mx, off, 64));
        float sum = 0.f;
#pragma unroll
        for (int j = 0; j < 8; ++j) {
            const float e = __expf(r[j] - mx);
            weiT[lane + 64 * j][wv] = e;
            sum += e;
        }
#pragma unroll
        for (int off = 1; off < 64; off <<= 1)
            sum += __shfl_xor(sum, off, 64);
        if (lane == 0) invs[wv] = 1.f / sum;
    }
    __syncthreads();

    // ---- phase 2: PV, wave wv covers 64 t, sliding v registers ----
    {
        const int t0r = wv * 64;
        const float* vb = vbuf + ((size_t)b * SS + w0 + t0r) * DD + lane;
        float p0 = 0.f, p1 = 0.f, p2 = 0.f, p3 = 0.f;
        float v0 = vb[0], v1 = vb[DD], v2 = vb[2 * DD];
#pragma unroll 4
        for (int t = 0; t < 64; ++t) {
            const float v3 = vb[(size_t)(t + 3) * DD];
            const f4 w4 = *(const f4*)&weiT[t0r + t][0];
            p0 = fmaf(w4[0], v0, p0);
            p1 = fmaf(w4[1], v1, p1);
            p2 = fmaf(w4[2], v2, p2);
            p3 = fmaf(w4[3], v3, p3);
            v0 = v1; v1 = v2; v2 = v3;
        }
        partial[wv][0][lane] = p0;
        partial[wv][1][lane] = p1;
        partial[wv][2][lane] = p2;
        partial[wv][3][lane] = p3;
    }
    __syncthreads();

    // ---- final reduce + store ----
    if (tid < WT * DD) {
        const int m = tid >> 6, dd = tid & 63;
        float o = 0.f;
#pragma unroll
        for (int j = 0; j < 8; ++j) o += partial[j][m][dd];
        out[((size_t)b * TT + w0 + m) * DD + dd] = o * invs[m];
    }
}

// ---------------------------------------------------------------------------
extern "C" void kernel_launch(void* const* d_in, const int* in_sizes, int n_in,
                              void* d_out, int out_size, void* d_ws, size_t ws_size,
                              hipStream_t stream) {
    const float* x    = (const float*)d_in[0];
    const float* Wk   = (const float*)d_in[1];
    const float* Wv   = (const float*)d_in[2];
    const float* Wq   = (const float*)d_in[3];
    const float* bias = (const float*)d_in[4];
    float* out = (float*)d_out;

    float* kT   = (float*)d_ws;                     // DD*NROW
    float* vbuf = kT + (size_t)DD * NROW;           // NROW*DD
    float* qbuf = vbuf + (size_t)NROW * DD;         // BB*TT*DD

    proj_kernel<<<PBLOCKS, 512, 0, stream>>>(x, Wk, Wv, Wq, kT, vbuf, qbuf);
    attn_kernel<<<BB * TT / WT, 512, 0, stream>>>(kT, vbuf, qbuf, bias, out);
}

// Round 7
// 137.069 us; speedup vs baseline: 4.0254x; 4.0254x over previous
//
#include <hip/hip_runtime.h>
#include <hip/hip_bf16.h>

#define BB 4      // batch
#define SS 1023   // source length = 2T-1
#define TT 512    // window length
#define CC 1024   // embed dim
#define DD 64     // head size
#define NROW (BB*SS)    // 4092
#define PR 8            // proj rows per block
#define PBLOCKS ((NROW + PR - 1) / PR)   // 512

typedef float f4 __attribute__((ext_vector_type(4)));

// ---------------------------------------------------------------------------
// Kernel 1: projections k|v|q = x @ [Wk|Wv|Wq].
// 512 blocks x 512 threads (8 waves). Block owns PR=8 x-rows staged once in
// 32 KB LDS. Wave wv covers K-slice [128wv, 128wv+128); lane = output d.
// W loads software-pipelined through two register banks (A/B) written INLINE
// (no lambdas / array params -> round 6's scratch-spill disaster is avoided;
// constant-indexed arrays under #pragma unroll SROA to registers).
// k stored transposed kT[d][row] for coalesced attn phase-1.
// ---------------------------------------------------------------------------
__global__ __launch_bounds__(512) void proj_kernel(
    const float* __restrict__ x,
    const float* __restrict__ Wk,
    const float* __restrict__ Wv,
    const float* __restrict__ Wq,
    float* __restrict__ kT,     // [DD][NROW]
    float* __restrict__ vbuf,   // [NROW][DD]
    float* __restrict__ qbuf)   // [BB*TT][DD]
{
    __shared__ __align__(16) float smem[PR * CC];   // 32 KB; later red[4][1536]

    const int tid  = threadIdx.x;
    const int lane = tid & 63;
    const int wv   = tid >> 6;              // 0..7
    const int bs0  = blockIdx.x * PR;
    const int nr   = (NROW - bs0 < PR) ? (NROW - bs0) : PR;
    const int s0   = bs0 % SS;
    const bool needq = (s0 + PR - 1) >= (TT - 1);

    // ---- stage x panel: 8 rows x 1024 floats, coalesced f4 ----
    {
        const f4* xg = (const f4*)x;
        f4* xs4 = (f4*)smem;
#pragma unroll
        for (int j = 0; j < 4; ++j) {
            const int idx = tid + j * 512;         // 0..2047
            const int r = idx >> 8, c4 = idx & 255;
            int g = bs0 + r; if (g > NROW - 1) g = NROW - 1;
            xs4[idx] = xg[(size_t)g * (CC / 4) + c4];
        }
    }
    __syncthreads();

    float accK[PR], accV[PR], accQ[PR];
#pragma unroll
    for (int r = 0; r < PR; ++r) { accK[r] = 0.f; accV[r] = 0.f; accQ[r] = 0.f; }

    const int c0 = wv * 128;
    const float* wkp = Wk + (size_t)c0 * DD + lane;
    const float* wvp = Wv + (size_t)c0 * DD + lane;
    const float* wqp = Wq + (size_t)c0 * DD + lane;

    float wkA[4], wlA[4], wqA[4], wkB[4], wlB[4], wqB[4];

    // preload bank A for c4 = 0
#pragma unroll
    for (int kk = 0; kk < 4; ++kk) {
        wkA[kk] = wkp[kk * DD];
        wlA[kk] = wvp[kk * DD];
    }
    if (needq) {
#pragma unroll
        for (int kk = 0; kk < 4; ++kk) wqA[kk] = wqp[kk * DD];
    }

    for (int c4 = 0; c4 < 32; c4 += 2) {
        // ---- prefetch bank B (c4+1) ----
#pragma unroll
        for (int kk = 0; kk < 4; ++kk) {
            const int cl = (c4 + 1) * 4 + kk;
            wkB[kk] = wkp[cl * DD];
            wlB[kk] = wvp[cl * DD];
        }
        if (needq) {
#pragma unroll
            for (int kk = 0; kk < 4; ++kk)
                wqB[kk] = wqp[((c4 + 1) * 4 + kk) * DD];
        }
        // ---- compute with bank A (c4) ----
        {
            f4 xv[PR];
#pragma unroll
            for (int r = 0; r < PR; ++r)
                xv[r] = *(const f4*)&smem[r * CC + c0 + c4 * 4];
#pragma unroll
            for (int kk = 0; kk < 4; ++kk)
#pragma unroll
                for (int r = 0; r < PR; ++r) {
                    accK[r] = fmaf(xv[r][kk], wkA[kk], accK[r]);
                    accV[r] = fmaf(xv[r][kk], wlA[kk], accV[r]);
                }
            if (needq) {
#pragma unroll
                for (int kk = 0; kk < 4; ++kk)
#pragma unroll
                    for (int r = 0; r < PR; ++r)
                        accQ[r] = fmaf(xv[r][kk], wqA[kk], accQ[r]);
            }
        }
        // ---- prefetch bank A (c4+2); tail wraps to 0 (harmless reload) ----
        {
            const int c4n = (c4 + 2 < 32) ? (c4 + 2) : 0;
#pragma unroll
            for (int kk = 0; kk < 4; ++kk) {
                const int cl = c4n * 4 + kk;
                wkA[kk] = wkp[cl * DD];
                wlA[kk] = wvp[cl * DD];
            }
            if (needq) {
#pragma unroll
                for (int kk = 0; kk < 4; ++kk)
                    wqA[kk] = wqp[(c4n * 4 + kk) * DD];
            }
        }
        // ---- compute with bank B (c4+1) ----
        {
            f4 xv[PR];
#pragma unroll
            for (int r = 0; r < PR; ++r)
                xv[r] = *(const f4*)&smem[r * CC + c0 + (c4 + 1) * 4];
#pragma unroll
            for (int kk = 0; kk < 4; ++kk)
#pragma unroll
                for (int r = 0; r < PR; ++r) {
                    accK[r] = fmaf(xv[r][kk], wkB[kk], accK[r]);
                    accV[r] = fmaf(xv[r][kk], wlB[kk], accV[r]);
                }
            if (needq) {
#pragma unroll
                for (int kk = 0; kk < 4; ++kk)
#pragma unroll
                    for (int r = 0; r < PR; ++r)
                        accQ[r] = fmaf(xv[r][kk], wqB[kk], accQ[r]);
            }
        }
    }
    __syncthreads();            // x panel no longer needed -> reuse as red

    // ---- cross-wave reduction: red[4][1536], waves 4-7 add onto 0-3 ----
    float* red = smem;
    const int base = (wv & 3) * 1536;
    if (wv < 4) {
#pragma unroll
        for (int r = 0; r < PR; ++r) {
            red[base + lane * PR + r]        = accK[r];   // k: [d][r]
            red[base + 512 + r * DD + lane]  = accV[r];   // v: [r][d]
        }
        if (needq)
#pragma unroll
            for (int r = 0; r < PR; ++r)
                red[base + 1024 + r * DD + lane] = accQ[r];
    }
    __syncthreads();
    if (wv >= 4) {
#pragma unroll
        for (int r = 0; r < PR; ++r) {
            red[base + lane * PR + r]       += accK[r];
            red[base + 512 + r * DD + lane] += accV[r];
        }
        if (needq)
#pragma unroll
            for (int r = 0; r < PR; ++r)
                red[base + 1024 + r * DD + lane] += accQ[r];
    }
    __syncthreads();

    // ---- final 4-way sum + stores ----
    const int nslots = needq ? 1536 : 1024;
    for (int slot = tid; slot < nslots; slot += 512) {
        const float s = red[slot] + red[slot + 1536] +
                        red[slot + 3072] + red[slot + 4608];
        if (slot < 512) {
            const int dd = slot >> 3, r = slot & 7;
            if (r < nr) kT[(size_t)dd * NROW + bs0 + r] = s;
        } else if (slot < 1024) {
            const int i = slot - 512, r = i >> 6, dd = i & 63;
            if (r < nr) vbuf[(size_t)(bs0 + r) * DD + dd] = s;
        } else {
            const int i = slot - 1024, r = i >> 6, dd = i & 63;
            if (r < nr) {
                const int bs = bs0 + r;
                const int b = bs / SS, ss = bs - b * SS;
                if (ss >= TT - 1)
                    qbuf[((size_t)b * TT + (ss - (TT - 1))) * DD + dd] = s;
            }
        }
    }
}

// ---------------------------------------------------------------------------
// Kernel 2: attention per (b, w) — 2048 blocks x 256 threads (the measured
// best regime, round 4), coalesced kT reads, bias folded into the logit FMA.
// ---------------------------------------------------------------------------
__global__ __launch_bounds__(256) void attn_kernel(
    const float* __restrict__ kT,     // [DD][NROW]
    const float* __restrict__ vbuf,   // [NROW][DD]
    const float* __restrict__ qbuf,   // [BB*TT][DD]
    const float* __restrict__ bias,   // [DD][TT]
    float* __restrict__ out)          // [BB*TT][DD]
{
    __shared__ float qs[DD];
    __shared__ float wei[TT];
    __shared__ float red[8];
    __shared__ float partial[4][DD];

    const int bw  = blockIdx.x;
    const int b   = bw >> 9;
    const int w   = bw & (TT - 1);
    const int tid = threadIdx.x;
    const int wave = tid >> 6;
    const int lane = tid & 63;

    if (tid < DD) qs[tid] = qbuf[(size_t)bw * DD + tid];
    __syncthreads();

    // ---- phase 1: logits, coalesced in t ----
    const float* kcol = kT + (size_t)b * SS + w;
    float acc0 = 0.f, acc1 = 0.f;
#pragma unroll 4
    for (int dd = 0; dd < DD; ++dd) {
        const float q  = qs[dd];
        const float k0 = kcol[(size_t)dd * NROW + tid];
        const float k1 = kcol[(size_t)dd * NROW + tid + 256];
        const float b0 = bias[dd * TT + tid];
        const float b1 = bias[dd * TT + tid + 256];
        acc0 = fmaf(q, k0 + b0, acc0);
        acc1 = fmaf(q, k1 + b1, acc1);
    }

    // ---- block max ----
    float m = fmaxf(acc0, acc1);
#pragma unroll
    for (int off = 32; off; off >>= 1)
        m = fmaxf(m, __shfl_down(m, off, 64));
    if (lane == 0) red[wave] = m;
    __syncthreads();
    m = fmaxf(fmaxf(red[0], red[1]), fmaxf(red[2], red[3]));

    // ---- exp + block sum ----
    const float e0 = __expf(acc0 - m);
    const float e1 = __expf(acc1 - m);
    wei[tid]       = e0;
    wei[tid + 256] = e1;
    float ssum = e0 + e1;
#pragma unroll
    for (int off = 32; off; off >>= 1)
        ssum += __shfl_down(ssum, off, 64);
    if (lane == 0) red[4 + wave] = ssum;
    __syncthreads();
    const float inv = 1.f / (red[4] + red[5] + red[6] + red[7]);

    // ---- phase 2: out[d] = sum_t wei[t] * v[b, w+t, d]  (coalesced) ----
    {
        const int dd = lane;
        float a = 0.f;
        const float* vbase = vbuf + ((size_t)(b * SS + w)) * DD + dd;
        const int t0 = wave * 128;
#pragma unroll 4
        for (int t = t0; t < t0 + 128; ++t)
            a = fmaf(wei[t], vbase[(size_t)t * DD], a);
        partial[wave][dd] = a;
    }
    __syncthreads();

    if (tid < DD) {
        const float o = (partial[0][tid] + partial[1][tid] +
                         partial[2][tid] + partial[3][tid]) * inv;
        out[(size_t)bw * DD + tid] = o;
    }
}

// ---------------------------------------------------------------------------
extern "C" void kernel_launch(void* const* d_in, const int* in_sizes, int n_in,
                              void* d_out, int out_size, void* d_ws, size_t ws_size,
                              hipStream_t stream) {
    const float* x    = (const float*)d_in[0];
    const float* Wk   = (const float*)d_in[1];
    const float* Wv   = (const float*)d_in[2];
    const float* Wq   = (const float*)d_in[3];
    const float* bias = (const float*)d_in[4];
    float* out = (float*)d_out;

    float* kT   = (float*)d_ws;                     // DD*NROW
    float* vbuf = kT + (size_t)DD * NROW;           // NROW*DD
    float* qbuf = vbuf + (size_t)NROW * DD;         // BB*TT*DD

    proj_kernel<<<PBLOCKS, 512, 0, stream>>>(x, Wk, Wv, Wq, kT, vbuf, qbuf);
    attn_kernel<<<BB * TT, 256, 0, stream>>>(kT, vbuf, qbuf, bias, out);
}